// Round 4
// baseline (931.093 us; speedup 1.0000x reference)
//
#include <hip/hip_runtime.h>
#include <hip/hip_bf16.h>

#define TOKENS 32768
#define NEXP   16
#define HID    2048
#define IMD    1408
#define BM 256
#define BK 64

typedef __bf16 bf16x8 __attribute__((ext_vector_type(8)));
typedef float  f32x4  __attribute__((ext_vector_type(4)));
typedef unsigned short u16x8 __attribute__((ext_vector_type(8)));

using gptr1_t = const __attribute__((address_space(1))) void*;
using lptr3_t = __attribute__((address_space(3))) void*;

static __device__ __forceinline__ unsigned short f2bf(float f) {
  unsigned int x = __builtin_bit_cast(unsigned int, f);
  x += 0x7fffu + ((x >> 16) & 1u);   // round-to-nearest-even
  return (unsigned short)(x >> 16);
}
static __device__ __forceinline__ float bf2f(unsigned short u) {
  unsigned int x = ((unsigned int)u) << 16;
  return __builtin_bit_cast(float, x);
}
static __device__ __forceinline__ void gload16(const void* g, void* l) {
  __builtin_amdgcn_global_load_lds((gptr1_t)g, (lptr3_t)l, 16, 0, 0);
}
static __device__ __forceinline__ void vwait(int n) {
  switch (n) {
    case 0:  asm volatile("s_waitcnt vmcnt(0)" ::: "memory"); break;
    case 2:  asm volatile("s_waitcnt vmcnt(2)" ::: "memory"); break;
    default: asm volatile("s_waitcnt vmcnt(6)" ::: "memory"); break;
  }
}

// ---------------- f32 -> bf16 straight convert (x) ----------------
__global__ __launch_bounds__(256)
void convert_kernel(const float* __restrict__ in, unsigned short* __restrict__ out, size_t n)
{
  size_t i = ((size_t)blockIdx.x * blockDim.x + threadIdx.x) * 8;
  if (i >= n) return;
  float4 a = *(const float4*)(in + i);
  float4 b = *(const float4*)(in + i + 4);
  u16x8 o;
  o[0] = f2bf(a.x); o[1] = f2bf(a.y); o[2] = f2bf(a.z); o[3] = f2bf(a.w);
  o[4] = f2bf(b.x); o[5] = f2bf(b.y); o[6] = f2bf(b.z); o[7] = f2bf(b.w);
  *(u16x8*)(out + i) = o;
}

// ------------- f32 [E][K][N] -> bf16 [E][N][K] transpose-convert -------------
__global__ __launch_bounds__(256)
void transpose_conv_kernel(const float* __restrict__ in, unsigned short* __restrict__ out,
                           int K, int N)
{
  __shared__ float tile[32][33];
  const int e = blockIdx.z;
  const float* ip = in + (size_t)e * K * N;
  unsigned short* op = out + (size_t)e * K * N;
  const int c0 = blockIdx.x * 32, r0 = blockIdx.y * 32;
  const int tx = threadIdx.x, ty = threadIdx.y;
#pragma unroll
  for (int i = 0; i < 4; ++i)
    tile[ty + 8 * i][tx] = ip[(size_t)(r0 + ty + 8 * i) * N + c0 + tx];
  __syncthreads();
#pragma unroll
  for (int i = 0; i < 4; ++i)
    op[(size_t)(c0 + ty + 8 * i) * K + r0 + tx] = f2bf(tile[tx][ty + 8 * i]);
}

// ======== grouped GEMM, 256x256 tile, BK=64, 4 fine phases per K-tile ========
// m201-style schedule: per phase {ds_read frags | stage half-tile | barrier |
// lgkmcnt(0) | setprio(1) 16xMFMA setprio(0) | [vmcnt(2)] | barrier}.
//
// LDS row permutation: A lds-row = mh*128 + wr*64 + (mf*16+fr)
//                      (global row = wr*128 + mh*64 + mf*16 + fr)
//                      B lds-row = nh*128 + wc*32 + (nf&1)*16 + fr
// so phase operand sets are contiguous 128-row staging chunks.
// Slot swizzle (both sides): 16B slot s of row r stored at s ^ (r&7).
//
// MODE 0: fused gate+up. B-tile col v (0..255): v = q*32 + p*16 + i ->
//         matrix p (0=gate,1=up), global col ct*128 + q*16 + i.
//         Epilogue: h = bf16(silu(acc[mi][2m]) * acc[mi][2m+1]).
// MODE 1: down, plain BN=256, f32 out.
template<int MODE>
__global__ __launch_bounds__(512, 2)
void gemm_kernel(const unsigned short* __restrict__ A,
                 const unsigned short* __restrict__ B0,
                 const unsigned short* __restrict__ B1,
                 unsigned short* __restrict__ Hc,
                 float* __restrict__ Cf,
                 const int* __restrict__ gs,
                 int K, int N)
{
  constexpr int NRT = TOKENS / BM;   // 128 row tiles

  __shared__ __align__(16) unsigned short lA[2][256 * 64];  // 64 KiB
  __shared__ __align__(16) unsigned short lB[2][256 * 64];  // 64 KiB

  // bijective XCD swizzle (grids are %8==0); row-tile fastest -> per-XCD
  // chunk shares one B panel
  const int nwg = gridDim.x;
  const int q = nwg >> 3;
  const int wgid = (blockIdx.x & 7) * q + (blockIdx.x >> 3);
  const int rt = wgid % NRT;
  const int ct = wgid / NRT;
  const int row0 = rt * BM;

  int e = 0;
  { int a0 = 0;
    for (int i = 0; i < NEXP; ++i) { int s = gs[i]; if (row0 < a0 + s) { e = i; break; } a0 += s; } }

  const unsigned short* Ap = A + (size_t)row0 * K;
  const unsigned short* Bg = B0 + (size_t)e * N * K;
  const unsigned short* Bu = (MODE == 0) ? (B1 + (size_t)e * N * K) : nullptr;

  const int tid  = threadIdx.x;
  const int lane = tid & 63, wave = tid >> 6;
  const int wr = wave >> 2, wc = wave & 3;   // 2 M-waves x 4 N-waves, 128x64/wave
  const int fr = lane & 15, fq = lane >> 4;

  // swizzled fragment-read byte-slot (elements): slot = (kk*4+fq) ^ (fr&7)
  const int csw0 = ((0 * 4 + fq) ^ (fr & 7)) * 8;
  const int csw1 = ((1 * 4 + fq) ^ (fr & 7)) * 8;

  // staging: per gload16 sweep, lane covers row (..+lane>>3), slot lane&7;
  // logical slot = (lane&7) ^ ((lane>>3)&7) -> pre-swizzled global column
  const int r8   = lane >> 3;
  const int slog = ((lane & 7) ^ (r8 & 7)) * 8;

  const int nt = K / BK;

  f32x4 acc[8][4] = {};

  // stage one 128-row chunk (2 x gload16/thread).
  // chunk: 0 = B_nh0, 1 = B_nh1, 2 = A_mh0, 3 = A_mh1
  auto stage = [&](int chunk, int tt) {
    const int buf = tt & 1;
    const int k0 = tt * BK;
#pragma unroll
    for (int w = 0; w < 2; ++w) {
      if (chunk >= 2) {
        const int mh = chunk - 2;
        unsigned short* ldst = &lA[buf][(mh * 128 + w * 64 + wave * 8) * 64];
        const int grow = w * 128 + mh * 64 + wave * 8 + r8;
        gload16(Ap + (size_t)grow * K + k0 + slog, ldst);
      } else {
        const int h = chunk;
        unsigned short* ldst = &lB[buf][(h * 128 + w * 64 + wave * 8) * 64];
        const int rem = w * 64 + wave * 8 + r8;     // 0..127
        const int wcs = rem >> 5, rr = rem & 31;
        if constexpr (MODE == 0) {
          const int gcol = ct * 128 + (wcs * 2 + h) * 16 + (rr & 15);
          const unsigned short* mb = ((rr >> 4) & 1) ? Bu : Bg;
          gload16(mb + (size_t)gcol * K + k0 + slog, ldst);
        } else {
          const int gcol = ct * 256 + wcs * 64 + h * 32 + rr;
          gload16(Bg + (size_t)gcol * K + k0 + slog, ldst);
        }
      }
    }
  };

  // one fine phase: quadrant (mh, kk). readB: load b-frags for this kk.
  bf16x8 a[4], b[4];
  auto phase = [&](int cur, int mh, int kk, bool readB,
                   int stChunk, int tN, bool doStage, int waitN) {
    const unsigned short* Ab = lA[cur];
    const unsigned short* Bb = lB[cur];
    const int csw = kk ? csw1 : csw0;
#pragma unroll
    for (int mf = 0; mf < 4; ++mf)
      a[mf] = *(const bf16x8*)(Ab + (mh * 128 + wr * 64 + mf * 16 + fr) * 64 + csw);
    if (readB) {
#pragma unroll
      for (int nf = 0; nf < 4; ++nf)
        b[nf] = *(const bf16x8*)(Bb + ((nf >> 1) * 128 + wc * 32 + (nf & 1) * 16 + fr) * 64 + csw);
    }
    if (doStage) stage(stChunk, tN);
    __builtin_amdgcn_s_barrier();
    asm volatile("s_waitcnt lgkmcnt(0)" ::: "memory");
    __builtin_amdgcn_s_setprio(1);
#pragma unroll
    for (int mf = 0; mf < 4; ++mf)
#pragma unroll
      for (int nf = 0; nf < 4; ++nf)
        acc[mh * 4 + mf][nf] =
            __builtin_amdgcn_mfma_f32_16x16x32_bf16(a[mf], b[nf], acc[mh * 4 + mf][nf], 0, 0, 0);
    __builtin_amdgcn_s_setprio(0);
    if (waitN >= 0) vwait(waitN);
    __builtin_amdgcn_s_barrier();
  };

  // prologue: tile 0 fully staged, drained once
  stage(0, 0); stage(1, 0); stage(2, 0); stage(3, 0);
  vwait(0);
  __builtin_amdgcn_s_barrier();

  for (int t = 0; t < nt; ++t) {
    const int cur = t & 1;
    const bool more = (t + 1 < nt);
    // φ0 (kk0,mh0): read a,b | stage B0(t+1) | W2: A1(t) landed (vmcnt(2))
    phase(cur, 0, 0, true,  0, t + 1, more, more ? 2 : 0);
    // φ1 (kk0,mh1): read a   | stage B1(t+1)
    phase(cur, 1, 0, false, 1, t + 1, more, -1);
    // φ2 (kk1,mh0): read a,b | stage A0(t+1)
    phase(cur, 0, 1, true,  2, t + 1, more, -1);
    // φ3 (kk1,mh1): read a   | stage A1(t+1) | W1: B0,B1,A0(t+1) landed
    phase(cur, 1, 1, false, 3, t + 1, more, more ? 2 : -1);
  }

  // epilogue. C/D frag layout: col = lane&15, row = fq*4 + reg (m89-verified)
  // acc[mi][nf]: global row = row0 + wr*128 + (mi>>2)*64 + (mi&3)*16 + fq*4 + reg
#pragma unroll
  for (int mi = 0; mi < 8; ++mi) {
    const int rowb = row0 + wr * 128 + (mi >> 2) * 64 + (mi & 3) * 16 + fq * 4;
    if constexpr (MODE == 0) {
#pragma unroll
      for (int m2 = 0; m2 < 2; ++m2) {
        const int col = ct * 128 + (wc * 2 + m2) * 16 + fr;
        f32x4 g = acc[mi][2 * m2], u = acc[mi][2 * m2 + 1];
#pragma unroll
        for (int r = 0; r < 4; ++r) {
          float gv = g[r];
          float s = gv / (1.f + __expf(-gv)) * u[r];
          Hc[(size_t)(rowb + r) * N + col] = f2bf(s);
        }
      }
    } else {
#pragma unroll
      for (int nf = 0; nf < 4; ++nf) {
        const int col = ct * 256 + wc * 64 + nf * 16 + fr;
        f32x4 v = acc[mi][nf];
#pragma unroll
        for (int r = 0; r < 4; ++r)
          Cf[(size_t)(rowb + r) * N + col] = v[r];
      }
    }
  }
}

extern "C" void kernel_launch(void* const* d_in, const int* in_sizes, int n_in,
                              void* d_out, int out_size, void* d_ws, size_t ws_size,
                              hipStream_t stream)
{
  const float* x  = (const float*)d_in[0];
  const float* wg = (const float*)d_in[1];
  const float* wu = (const float*)d_in[2];
  const float* wd = (const float*)d_in[3];
  const int*   gs = (const int*)d_in[4];
  float* out = (float*)d_out;

  const size_t SZ_XB = (size_t)TOKENS * HID * 2;        // 134,217,728
  const size_t SZ_W  = (size_t)NEXP * HID * IMD * 2;    //  92,274,688
  const size_t SZ_H  = (size_t)TOKENS * IMD * 2;        //  92,274,688
  if (ws_size < SZ_XB + 2 * SZ_W + SZ_H) return;        // (empirically 411MB+ available)

  char* ws = (char*)d_ws;
  unsigned short* xb  = (unsigned short*)ws;
  unsigned short* wTg = (unsigned short*)(ws + SZ_XB);
  unsigned short* wTu = (unsigned short*)(ws + SZ_XB + SZ_W);
  unsigned short* h   = (unsigned short*)(ws + SZ_XB + 2 * SZ_W);

  const int cvt_grid = (int)(((size_t)TOKENS * HID) / (256 * 8));
  convert_kernel<<<cvt_grid, 256, 0, stream>>>(x, xb, (size_t)TOKENS * HID);

  transpose_conv_kernel<<<dim3(IMD / 32, HID / 32, NEXP), dim3(32, 8), 0, stream>>>(wg, wTg, HID, IMD);
  transpose_conv_kernel<<<dim3(IMD / 32, HID / 32, NEXP), dim3(32, 8), 0, stream>>>(wu, wTu, HID, IMD);
  gemm_kernel<0><<<(TOKENS / BM) * (IMD / 128), 512, 0, stream>>>(
      xb, wTg, wTu, h, nullptr, gs, HID, IMD);

  transpose_conv_kernel<<<dim3(HID / 32, IMD / 32, NEXP), dim3(32, 8), 0, stream>>>(wd, wTg, IMD, HID);
  gemm_kernel<1><<<(TOKENS / BM) * (HID / 256), 512, 0, stream>>>(
      h, wTg, nullptr, nullptr, out, gs, IMD, HID);
}